// Round 2
// baseline (643.019 us; speedup 1.0000x reference)
//
#include <hip/hip_runtime.h>
#include <math.h>

// ---------------- constants ----------------
#define BATCH 512
#define DIM 512
#define NCLS 100000
#define NB_TILES 782  // ceil(NCLS/128)
#define S_SCALE 64.0f
#define COS_M 0.8775825618903728f
#define SIN_M 0.479425538604203f
#define TH_C (-0.8775825618903728f)
#define MM_C 0.2397127693021015f
#define CLIP_LO (-1.0f + 1e-7f)
#define CLIP_HI (1.0f - 1e-7f)
#define LDA 72  // padded LDS row stride in shorts (144 B = 9 x 16 B)

typedef __attribute__((ext_vector_type(8))) short bf16x8;
typedef __attribute__((ext_vector_type(4))) float f32x4;

__device__ __forceinline__ unsigned int f2bf(float x) {
    union { float f; unsigned int u; } v;
    v.f = x;
    return (v.u + 0x7fffu + ((v.u >> 16) & 1u)) >> 16;
}
__device__ __forceinline__ unsigned int pack2(float lo, float hi) {
    return f2bf(lo) | (f2bf(hi) << 16);
}

// ---------------- kernel 1: normalize embeddings -> bf16, zero sumexp -------
__global__ void k_norm_e(const float* __restrict__ e, short* __restrict__ ebf,
                         float* __restrict__ sumexp) {
    int row = blockIdx.x;  // 512 rows
    int tid = threadIdx.x; // 128 threads, 4 floats each
    const float4* p = (const float4*)(e + (size_t)row * DIM);
    float4 v = p[tid];
    float ss = v.x * v.x + v.y * v.y + v.z * v.z + v.w * v.w;
    for (int m = 1; m < 64; m <<= 1) ss += __shfl_xor(ss, m, 64);
    __shared__ float wss[2];
    int wv = tid >> 6;
    if ((tid & 63) == 0) wss[wv] = ss;
    __syncthreads();
    float tot = wss[0] + wss[1];
    float inv = 1.0f / fmaxf(sqrtf(tot), 1e-12f);
    ushort4 o;
    o.x = (unsigned short)f2bf(v.x * inv);
    o.y = (unsigned short)f2bf(v.y * inv);
    o.z = (unsigned short)f2bf(v.z * inv);
    o.w = (unsigned short)f2bf(v.w * inv);
    ((ushort4*)(ebf + (size_t)row * DIM))[tid] = o;
    if (tid == 0) sumexp[row] = 0.0f;
}

// ---------------- kernel 2: fused GEMM + w-normalize + margin + sumexp ------
// grid = 98*32 = 3136 ; block = 256 (4 waves, 2x2 of 64x64)
// bx = group*32 + mb*8 + nbl  -> all 4 mb share bx%8 (same XCD, W L2 reuse)
__global__ __launch_bounds__(256, 3) void k_gemm(
    const short* __restrict__ ebf, const float* __restrict__ wgt,
    const int* __restrict__ labels, float* __restrict__ sumexp,
    float* __restrict__ phiS) {
    __shared__ __align__(16) short As[128 * LDA];
    __shared__ __align__(16) short Bs[128 * LDA];
    __shared__ int sLbl[128];
    __shared__ float sWn[128];

    int bx = blockIdx.x;
    int nb = (bx >> 5) * 8 + (bx & 7);
    if (nb >= NB_TILES) return;
    int mb = (bx >> 3) & 3;
    int n0 = nb * 128;

    int tid = threadIdx.x;
    int lane = tid & 63;
    int wv = tid >> 6;
    int wm = wv >> 1, wn = wv & 1;
    int quad = lane >> 4, l16 = lane & 15;

    if (tid < 128) sLbl[tid] = labels[mb * 128 + tid];

    // --- staging geometry ---
    // A (bf16): 4 chunks of 16B per thread per iter
    int arow = tid >> 3;       // 0..31 (+ i*32)
    int acol = (tid & 7) * 8;  // short index
    int boffA = (mb * 128 + arow) * DIM + acol;
    // B (fp32 source): 8 chunks of float4 per thread per iter
    int brow = tid >> 4;        // 0..15 (+ i*16)
    int bcol = (tid & 15) * 4;  // float index
    int boffB[8];
#pragma unroll
    for (int i = 0; i < 8; ++i) {
        int wr = n0 + i * 16 + brow;
        if (wr > NCLS - 1) wr = NCLS - 1;
        boffB[i] = wr * DIM + bcol;
    }

    f32x4 acc[4][4];
#pragma unroll
    for (int i = 0; i < 4; ++i)
#pragma unroll
        for (int j = 0; j < 4; ++j) acc[i][j] = (f32x4){0.f, 0.f, 0.f, 0.f};
    float ssq[8];
#pragma unroll
    for (int i = 0; i < 8; ++i) ssq[i] = 0.0f;

    // --- preload k-chunk 0 ---
    int4 ra[4];
    float4 rb[8];
#pragma unroll
    for (int i = 0; i < 4; ++i)
        ra[i] = *(const int4*)&ebf[boffA + i * 32 * DIM];
#pragma unroll
    for (int i = 0; i < 8; ++i) rb[i] = *(const float4*)&wgt[boffB[i]];

    int aoffL = (wm * 64 + l16) * LDA + quad * 8;  // A fragment base (shorts)
    int boffL = (wn * 64 + l16) * LDA + quad * 8;  // B fragment base

#pragma unroll
    for (int kc = 0; kc < 8; ++kc) {
        // ---- write current tiles to LDS (convert W fp32->bf16, track ssq) --
#pragma unroll
        for (int i = 0; i < 4; ++i)
            *(int4*)&As[(i * 32 + arow) * LDA + acol] = ra[i];
#pragma unroll
        for (int i = 0; i < 8; ++i) {
            float4 v = rb[i];
            ssq[i] += v.x * v.x + v.y * v.y + v.z * v.z + v.w * v.w;
            uint2 pk;
            pk.x = pack2(v.x, v.y);
            pk.y = pack2(v.z, v.w);
            *(uint2*)&Bs[(i * 16 + brow) * LDA + bcol] = pk;
        }
        // ---- prefetch next k-chunk into registers (stays in flight) --------
        if (kc < 7) {
#pragma unroll
            for (int i = 0; i < 4; ++i)
                ra[i] = *(const int4*)&ebf[boffA + i * 32 * DIM + (kc + 1) * 64];
#pragma unroll
            for (int i = 0; i < 8; ++i)
                rb[i] = *(const float4*)&wgt[boffB[i] + (kc + 1) * 64];
        }
        // raw barrier: waits own LDS writes only, leaves global loads in flight
        asm volatile("s_waitcnt lgkmcnt(0)\n\ts_barrier" ::: "memory");
        // ---- compute: 2 k-steps of 32 ----
#pragma unroll
        for (int ks = 0; ks < 2; ++ks) {
            bf16x8 af[4], bfr[4];
#pragma unroll
            for (int t = 0; t < 4; ++t)
                af[t] = *(const bf16x8*)&As[aoffL + t * 16 * LDA + ks * 32];
#pragma unroll
            for (int t = 0; t < 4; ++t)
                bfr[t] = *(const bf16x8*)&Bs[boffL + t * 16 * LDA + ks * 32];
#pragma unroll
            for (int tm = 0; tm < 4; ++tm)
#pragma unroll
                for (int tn = 0; tn < 4; ++tn)
                    acc[tm][tn] = __builtin_amdgcn_mfma_f32_16x16x32_bf16(
                        af[tm], bfr[tn], acc[tm][tn], 0, 0, 0);
        }
        // raw barrier: reads already drained per-wave by compiler before MFMA
        asm volatile("s_barrier" ::: "memory");
    }

    // ---- finalize W norms: reduce over the 16 threads sharing each row ----
#pragma unroll
    for (int i = 0; i < 8; ++i) {
        float s = ssq[i];
        s += __shfl_xor(s, 1, 64);
        s += __shfl_xor(s, 2, 64);
        s += __shfl_xor(s, 4, 64);
        s += __shfl_xor(s, 8, 64);
        if ((tid & 15) == 0) sWn[i * 16 + brow] = 1.0f / fmaxf(sqrtf(s), 1e-12f);
    }
    asm volatile("s_waitcnt lgkmcnt(0)\n\ts_barrier" ::: "memory");

    float wscale[4];
#pragma unroll
    for (int tn = 0; tn < 4; ++tn) wscale[tn] = sWn[wn * 64 + tn * 16 + l16];

    // ---- epilogue: scale, clip, margin on label col, exp, per-row reduce --
    float rowsum[16];
#pragma unroll
    for (int i = 0; i < 16; ++i) rowsum[i] = 0.0f;

#pragma unroll
    for (int tm = 0; tm < 4; ++tm) {
#pragma unroll
        for (int r = 0; r < 4; ++r) {
            int m_local = wm * 64 + tm * 16 + quad * 4 + r;
            int lbl = sLbl[m_local];
            float rs = 0.0f;
#pragma unroll
            for (int tn = 0; tn < 4; ++tn) {
                float c = acc[tm][tn][r] * wscale[tn];
                c = fminf(fmaxf(c, CLIP_LO), CLIP_HI);
                int col = n0 + wn * 64 + tn * 16 + l16;
                float t = c;
                if (col == lbl) {
                    float sn = sqrtf(fmaxf(1.0f - c * c, 0.0f));
                    float ph = c * COS_M - sn * SIN_M;
                    ph = (c > TH_C) ? ph : (c - MM_C);
                    t = ph;
                    phiS[mb * 128 + m_local] = S_SCALE * ph;
                }
                float ex = (col < NCLS) ? __expf(S_SCALE * t - 64.0f) : 0.0f;
                rs += ex;
            }
            rowsum[tm * 4 + r] = rs;
        }
    }
#pragma unroll
    for (int idx = 0; idx < 16; ++idx) {
        float v = rowsum[idx];
        v += __shfl_xor(v, 1, 64);
        v += __shfl_xor(v, 2, 64);
        v += __shfl_xor(v, 4, 64);
        v += __shfl_xor(v, 8, 64);
        if (l16 == idx) {
            int tm = idx >> 2, r = idx & 3;
            int m_local = wm * 64 + tm * 16 + quad * 4 + r;
            atomicAdd(&sumexp[mb * 128 + m_local], v);
        }
    }
}

// ---------------- kernel 3: nll + mean ----------------
__global__ void k_final(const float* __restrict__ sumexp,
                        const float* __restrict__ phiS,
                        float* __restrict__ out) {
    int tid = threadIdx.x;  // 512
    float nll = 64.0f + logf(sumexp[tid]) - phiS[tid];
    for (int m = 1; m < 64; m <<= 1) nll += __shfl_xor(nll, m, 64);
    __shared__ float ws[8];
    int wv = tid >> 6;
    if ((tid & 63) == 0) ws[wv] = nll;
    __syncthreads();
    if (tid == 0) {
        float s = 0.0f;
        for (int j = 0; j < 8; ++j) s += ws[j];
        out[0] = s / (float)BATCH;
    }
}

// ---------------- launch ----------------
extern "C" void kernel_launch(void* const* d_in, const int* in_sizes, int n_in,
                              void* d_out, int out_size, void* d_ws,
                              size_t ws_size, hipStream_t stream) {
    const float* emb = (const float*)d_in[0];
    const float* wgt = (const float*)d_in[1];
    const int* lbl = (const int*)d_in[2];

    char* ws = (char*)d_ws;
    short* ebf = (short*)ws;                      // 524,288 B
    float* sumexp = (float*)(ws + 524288);        // 2048 B
    float* phiS = (float*)(ws + 526336);          // 2048 B

    k_norm_e<<<dim3(BATCH), dim3(128), 0, stream>>>(emb, ebf, sumexp);
    k_gemm<<<dim3(3136), dim3(256), 0, stream>>>(ebf, wgt, lbl, sumexp, phiS);
    k_final<<<dim3(1), dim3(512), 0, stream>>>(sumexp, phiS, (float*)d_out);
}

// Round 3
// 535.700 us; speedup vs baseline: 1.2003x; 1.2003x over previous
//
#include <hip/hip_runtime.h>
#include <math.h>

// ---------------- constants ----------------
#define BATCH 512
#define DIM 512
#define NCLS 100000
#define NB_TILES 782  // ceil(NCLS/128)
#define S_SCALE 64.0f
#define COS_M 0.8775825618903728f
#define SIN_M 0.479425538604203f
#define TH_C (-0.8775825618903728f)
#define MM_C 0.2397127693021015f
#define CLIP_LO (-1.0f + 1e-7f)
#define CLIP_HI (1.0f - 1e-7f)
#define LDA 72  // padded LDS row stride in shorts (144 B = 9 x 16 B)

typedef __attribute__((ext_vector_type(8))) short bf16x8;
typedef __attribute__((ext_vector_type(4))) float f32x4;

__device__ __forceinline__ unsigned int f2bf(float x) {
    union { float f; unsigned int u; } v;
    v.f = x;
    return (v.u + 0x7fffu + ((v.u >> 16) & 1u)) >> 16;
}
__device__ __forceinline__ unsigned int pack2(float lo, float hi) {
    return f2bf(lo) | (f2bf(hi) << 16);
}

// ---------------- kernel 1: normalize embeddings -> bf16, zero sumexp -------
__global__ void k_norm_e(const float* __restrict__ e, short* __restrict__ ebf,
                         float* __restrict__ sumexp) {
    int row = blockIdx.x;  // 512 rows
    int tid = threadIdx.x; // 128 threads, 4 floats each
    const float4* p = (const float4*)(e + (size_t)row * DIM);
    float4 v = p[tid];
    float ss = v.x * v.x + v.y * v.y + v.z * v.z + v.w * v.w;
    for (int m = 1; m < 64; m <<= 1) ss += __shfl_xor(ss, m, 64);
    __shared__ float wss[2];
    int wv = tid >> 6;
    if ((tid & 63) == 0) wss[wv] = ss;
    __syncthreads();
    float tot = wss[0] + wss[1];
    float inv = 1.0f / fmaxf(sqrtf(tot), 1e-12f);
    ushort4 o;
    o.x = (unsigned short)f2bf(v.x * inv);
    o.y = (unsigned short)f2bf(v.y * inv);
    o.z = (unsigned short)f2bf(v.z * inv);
    o.w = (unsigned short)f2bf(v.w * inv);
    ((ushort4*)(ebf + (size_t)row * DIM))[tid] = o;
    if (tid == 0) sumexp[row] = 0.0f;
}

// ---------------- kernel 2: fused GEMM + w-normalize + margin + sumexp ------
// grid = 98*32 = 3136 ; block = 256 (4 waves, 2x2 of 64x64)
// bx = group*32 + mb*8 + nbl  -> all 4 mb share bx%8 (same XCD, W L2 reuse)
// launch_bounds(256,2): 256-reg unified cap. (256,3) forced a 1KB/thread
// scratch spill (R2: WRITE_SIZE 822 MB = 1024 B/thread exactly) that made
// the kernel spill-traffic-bound at 2.8 TB/s.
__global__ __launch_bounds__(256, 2) void k_gemm(
    const short* __restrict__ ebf, const float* __restrict__ wgt,
    const int* __restrict__ labels, float* __restrict__ sumexp,
    float* __restrict__ phiS) {
    __shared__ __align__(16) short As[128 * LDA];
    __shared__ __align__(16) short Bs[128 * LDA];
    __shared__ int sLbl[128];
    __shared__ float sWn[128];

    int bx = blockIdx.x;
    int nb = (bx >> 5) * 8 + (bx & 7);
    if (nb >= NB_TILES) return;
    int mb = (bx >> 3) & 3;
    int n0 = nb * 128;

    int tid = threadIdx.x;
    int lane = tid & 63;
    int wv = tid >> 6;
    int wm = wv >> 1, wn = wv & 1;
    int quad = lane >> 4, l16 = lane & 15;

    if (tid < 128) sLbl[tid] = labels[mb * 128 + tid];

    // --- staging geometry ---
    // A (bf16): 4 chunks of 16B per thread per iter
    int arow = tid >> 3;       // 0..31 (+ i*32)
    int acol = (tid & 7) * 8;  // short index
    int boffA = (mb * 128 + arow) * DIM + acol;
    // B (fp32 source): 8 chunks of float4 per thread per iter
    int brow = tid >> 4;        // 0..15 (+ i*16)
    int bcol = (tid & 15) * 4;  // float index
    int boffB[8];
#pragma unroll
    for (int i = 0; i < 8; ++i) {
        int wr = n0 + i * 16 + brow;
        if (wr > NCLS - 1) wr = NCLS - 1;
        boffB[i] = wr * DIM + bcol;
    }

    f32x4 acc[4][4];
#pragma unroll
    for (int i = 0; i < 4; ++i)
#pragma unroll
        for (int j = 0; j < 4; ++j) acc[i][j] = (f32x4){0.f, 0.f, 0.f, 0.f};
    float ssq[8];
#pragma unroll
    for (int i = 0; i < 8; ++i) ssq[i] = 0.0f;

    // --- preload k-chunk 0 ---
    int4 ra[4];
    float4 rb[8];
#pragma unroll
    for (int i = 0; i < 4; ++i)
        ra[i] = *(const int4*)&ebf[boffA + i * 32 * DIM];
#pragma unroll
    for (int i = 0; i < 8; ++i) rb[i] = *(const float4*)&wgt[boffB[i]];

    int aoffL = (wm * 64 + l16) * LDA + quad * 8;  // A fragment base (shorts)
    int boffL = (wn * 64 + l16) * LDA + quad * 8;  // B fragment base

#pragma unroll
    for (int kc = 0; kc < 8; ++kc) {
        // ---- write current tiles to LDS (convert W fp32->bf16, track ssq) --
#pragma unroll
        for (int i = 0; i < 4; ++i)
            *(int4*)&As[(i * 32 + arow) * LDA + acol] = ra[i];
#pragma unroll
        for (int i = 0; i < 8; ++i) {
            float4 v = rb[i];
            ssq[i] += v.x * v.x + v.y * v.y + v.z * v.z + v.w * v.w;
            uint2 pk;
            pk.x = pack2(v.x, v.y);
            pk.y = pack2(v.z, v.w);
            *(uint2*)&Bs[(i * 16 + brow) * LDA + bcol] = pk;
        }
        // ---- prefetch next k-chunk into registers (stays in flight) --------
        if (kc < 7) {
#pragma unroll
            for (int i = 0; i < 4; ++i)
                ra[i] = *(const int4*)&ebf[boffA + i * 32 * DIM + (kc + 1) * 64];
#pragma unroll
            for (int i = 0; i < 8; ++i)
                rb[i] = *(const float4*)&wgt[boffB[i] + (kc + 1) * 64];
        }
        // raw barrier: waits own LDS writes only, leaves global loads in flight
        asm volatile("s_waitcnt lgkmcnt(0)\n\ts_barrier" ::: "memory");
        // ---- compute: 2 k-steps of 32 ----
#pragma unroll
        for (int ks = 0; ks < 2; ++ks) {
            bf16x8 af[4], bfr[4];
#pragma unroll
            for (int t = 0; t < 4; ++t)
                af[t] = *(const bf16x8*)&As[aoffL + t * 16 * LDA + ks * 32];
#pragma unroll
            for (int t = 0; t < 4; ++t)
                bfr[t] = *(const bf16x8*)&Bs[boffL + t * 16 * LDA + ks * 32];
#pragma unroll
            for (int tm = 0; tm < 4; ++tm)
#pragma unroll
                for (int tn = 0; tn < 4; ++tn)
                    acc[tm][tn] = __builtin_amdgcn_mfma_f32_16x16x32_bf16(
                        af[tm], bfr[tn], acc[tm][tn], 0, 0, 0);
        }
        // raw barrier: reads already drained per-wave by compiler before MFMA
        asm volatile("s_barrier" ::: "memory");
    }

    // ---- finalize W norms: reduce over the 16 threads sharing each row ----
#pragma unroll
    for (int i = 0; i < 8; ++i) {
        float s = ssq[i];
        s += __shfl_xor(s, 1, 64);
        s += __shfl_xor(s, 2, 64);
        s += __shfl_xor(s, 4, 64);
        s += __shfl_xor(s, 8, 64);
        if ((tid & 15) == 0) sWn[i * 16 + brow] = 1.0f / fmaxf(sqrtf(s), 1e-12f);
    }
    asm volatile("s_waitcnt lgkmcnt(0)\n\ts_barrier" ::: "memory");

    float wscale[4];
#pragma unroll
    for (int tn = 0; tn < 4; ++tn) wscale[tn] = sWn[wn * 64 + tn * 16 + l16];

    // ---- epilogue: scale, clip, margin on label col, exp, per-row reduce --
    float rowsum[16];
#pragma unroll
    for (int i = 0; i < 16; ++i) rowsum[i] = 0.0f;

#pragma unroll
    for (int tm = 0; tm < 4; ++tm) {
#pragma unroll
        for (int r = 0; r < 4; ++r) {
            int m_local = wm * 64 + tm * 16 + quad * 4 + r;
            int lbl = sLbl[m_local];
            float rs = 0.0f;
#pragma unroll
            for (int tn = 0; tn < 4; ++tn) {
                float c = acc[tm][tn][r] * wscale[tn];
                c = fminf(fmaxf(c, CLIP_LO), CLIP_HI);
                int col = n0 + wn * 64 + tn * 16 + l16;
                float t = c;
                if (col == lbl) {
                    float sn = sqrtf(fmaxf(1.0f - c * c, 0.0f));
                    float ph = c * COS_M - sn * SIN_M;
                    ph = (c > TH_C) ? ph : (c - MM_C);
                    t = ph;
                    phiS[mb * 128 + m_local] = S_SCALE * ph;
                }
                float ex = (col < NCLS) ? __expf(S_SCALE * t - 64.0f) : 0.0f;
                rs += ex;
            }
            rowsum[tm * 4 + r] = rs;
        }
    }
#pragma unroll
    for (int idx = 0; idx < 16; ++idx) {
        float v = rowsum[idx];
        v += __shfl_xor(v, 1, 64);
        v += __shfl_xor(v, 2, 64);
        v += __shfl_xor(v, 4, 64);
        v += __shfl_xor(v, 8, 64);
        if (l16 == idx) {
            int tm = idx >> 2, r = idx & 3;
            int m_local = wm * 64 + tm * 16 + quad * 4 + r;
            atomicAdd(&sumexp[mb * 128 + m_local], v);
        }
    }
}

// ---------------- kernel 3: nll + mean ----------------
__global__ void k_final(const float* __restrict__ sumexp,
                        const float* __restrict__ phiS,
                        float* __restrict__ out) {
    int tid = threadIdx.x;  // 512
    float nll = 64.0f + logf(sumexp[tid]) - phiS[tid];
    for (int m = 1; m < 64; m <<= 1) nll += __shfl_xor(nll, m, 64);
    __shared__ float ws[8];
    int wv = tid >> 6;
    if ((tid & 63) == 0) ws[wv] = nll;
    __syncthreads();
    if (tid == 0) {
        float s = 0.0f;
        for (int j = 0; j < 8; ++j) s += ws[j];
        out[0] = s / (float)BATCH;
    }
}

// ---------------- launch ----------------
extern "C" void kernel_launch(void* const* d_in, const int* in_sizes, int n_in,
                              void* d_out, int out_size, void* d_ws,
                              size_t ws_size, hipStream_t stream) {
    const float* emb = (const float*)d_in[0];
    const float* wgt = (const float*)d_in[1];
    const int* lbl = (const int*)d_in[2];

    char* ws = (char*)d_ws;
    short* ebf = (short*)ws;                      // 524,288 B
    float* sumexp = (float*)(ws + 524288);        // 2048 B
    float* phiS = (float*)(ws + 526336);          // 2048 B

    k_norm_e<<<dim3(BATCH), dim3(128), 0, stream>>>(emb, ebf, sumexp);
    k_gemm<<<dim3(3136), dim3(256), 0, stream>>>(ebf, wgt, lbl, sumexp, phiS);
    k_final<<<dim3(1), dim3(512), 0, stream>>>(sumexp, phiS, (float*)d_out);
}

// Round 4
// 487.735 us; speedup vs baseline: 1.3184x; 1.0983x over previous
//
#include <hip/hip_runtime.h>
#include <math.h>

// ---------------- constants ----------------
#define BATCH 512
#define DIM 512
#define NCLS 100000
#define NB_TILES 782  // ceil(NCLS/128)
#define S_SCALE 64.0f
#define COS_M 0.8775825618903728f
#define SIN_M 0.479425538604203f
#define TH_C (-0.8775825618903728f)
#define MM_C 0.2397127693021015f
#define CLIP_LO (-1.0f + 1e-7f)
#define CLIP_HI (1.0f - 1e-7f)

typedef __attribute__((ext_vector_type(8))) short bf16x8;
typedef __attribute__((ext_vector_type(4))) float f32x4;

__device__ __forceinline__ unsigned int f2bf(float x) {
    union { float f; unsigned int u; } v;
    v.f = x;
    return (v.u + 0x7fffu + ((v.u >> 16) & 1u)) >> 16;
}

#define GLD16(gp, lp)                                                          \
    __builtin_amdgcn_global_load_lds(                                          \
        (const __attribute__((address_space(1))) void*)(gp),                   \
        (__attribute__((address_space(3))) void*)(lp), 16, 0, 0)

// ---------------- kernel 1: normalize embeddings -> bf16, zero sumexp -------
__global__ void k_norm_e(const float* __restrict__ e, short* __restrict__ ebf,
                         float* __restrict__ sumexpz) {
    int row = blockIdx.x;  // 512 rows
    int tid = threadIdx.x; // 128 threads, 4 floats each
    const float4* p = (const float4*)(e + (size_t)row * DIM);
    float4 v = p[tid];
    float ss = v.x * v.x + v.y * v.y + v.z * v.z + v.w * v.w;
    for (int m = 1; m < 64; m <<= 1) ss += __shfl_xor(ss, m, 64);
    __shared__ float wss[2];
    if ((tid & 63) == 0) wss[tid >> 6] = ss;
    __syncthreads();
    float inv = 1.0f / fmaxf(sqrtf(wss[0] + wss[1]), 1e-12f);
    ushort4 o;
    o.x = (unsigned short)f2bf(v.x * inv);
    o.y = (unsigned short)f2bf(v.y * inv);
    o.z = (unsigned short)f2bf(v.z * inv);
    o.w = (unsigned short)f2bf(v.w * inv);
    ((ushort4*)(ebf + (size_t)row * DIM))[tid] = o;
    if (tid == 0) sumexpz[row] = 0.0f;
}

// ---------------- kernel 2: normalize weight rows -> bf16 -------------------
// one wave per row; lane reads float4 at [lane] and [lane+64]
__global__ void k_norm_w(const float* __restrict__ w, short* __restrict__ wbf) {
    int wv = threadIdx.x >> 6;
    int lane = threadIdx.x & 63;
    int row = blockIdx.x * 4 + wv;  // 25000*4 == 100000
    const float4* p = (const float4*)(w + (size_t)row * DIM);
    float4 a = p[lane];
    float4 b = p[lane + 64];
    float ss = a.x * a.x + a.y * a.y + a.z * a.z + a.w * a.w +
               b.x * b.x + b.y * b.y + b.z * b.z + b.w * b.w;
    for (int m = 1; m < 64; m <<= 1) ss += __shfl_xor(ss, m, 64);
    float inv = 1.0f / fmaxf(sqrtf(ss), 1e-12f);
    ushort4 o0, o1;
    o0.x = (unsigned short)f2bf(a.x * inv); o0.y = (unsigned short)f2bf(a.y * inv);
    o0.z = (unsigned short)f2bf(a.z * inv); o0.w = (unsigned short)f2bf(a.w * inv);
    o1.x = (unsigned short)f2bf(b.x * inv); o1.y = (unsigned short)f2bf(b.y * inv);
    o1.z = (unsigned short)f2bf(b.z * inv); o1.w = (unsigned short)f2bf(b.w * inv);
    ushort4* q = (ushort4*)(wbf + (size_t)row * DIM);
    q[lane] = o0;
    q[lane + 64] = o1;
}

// ---------------- kernel 3: pipelined GEMM + margin + sumexp ----------------
// 128x128 tile, BK=64, double-buffered LDS via global_load_lds DMA.
// XOR-swizzled LDS layout (GLD16 forbids padding): LDS slot (row, g') holds
// global granule g' ^ (row&7); fragment reads use g ^ (l16&7).
// Pipeline: fills for kc and kc+1 in flight; gate on s_waitcnt vmcnt(8)
// (never 0 until tail) + raw s_barrier -> loads stay in flight across barriers.
__global__ __launch_bounds__(256) void k_gemm(
    const short* __restrict__ ebf, const short* __restrict__ wbf,
    const int* __restrict__ labels, float* __restrict__ sumexp,
    float* __restrict__ phiS) {
    __shared__ __align__(16) short As[2][128 * 64];
    __shared__ __align__(16) short Bs[2][128 * 64];
    __shared__ int sLbl[128];

    int bx = blockIdx.x;
    int nb = (bx >> 5) * 8 + (bx & 7);  // same-nb siblings share bx%8 (XCD)
    if (nb >= NB_TILES) return;
    int mb = (bx >> 3) & 3;
    int n0 = nb * 128;

    int tid = threadIdx.x;
    int lane = tid & 63;
    int wv = tid >> 6;
    int wm = wv >> 1, wn = wv & 1;
    int quad = lane >> 4, l16 = lane & 15;

    if (tid < 128) sLbl[tid] = labels[mb * 128 + tid];

    // --- DMA staging geometry: wave wv stages rows [wv*32, wv*32+32) ---
    int r_off = lane >> 3;           // 0..7 row within 8-row stripe
    int gsl = lane & 7;              // LDS slot granule
    int gsrc = gsl ^ r_off;          // swizzled source granule
    const short* gA = ebf + (size_t)(mb * 128 + wv * 32 + r_off) * DIM + gsrc * 8;
    const short* gB[4];
#pragma unroll
    for (int i = 0; i < 4; ++i) {
        int wr = n0 + wv * 32 + i * 8 + r_off;
        if (wr > NCLS - 1) wr = NCLS - 1;
        gB[i] = wbf + (size_t)wr * DIM + gsrc * 8;
    }

#define FILL(buf, kc_)                                                         \
    do {                                                                       \
        _Pragma("unroll") for (int i = 0; i < 4; ++i)                          \
            GLD16(gA + i * 8 * DIM + (kc_)*64, &As[buf][(wv * 32 + i * 8) * 64]); \
        _Pragma("unroll") for (int i = 0; i < 4; ++i)                          \
            GLD16(gB[i] + (kc_)*64, &Bs[buf][(wv * 32 + i * 8) * 64]);         \
    } while (0)

    f32x4 acc[4][4];
#pragma unroll
    for (int i = 0; i < 4; ++i)
#pragma unroll
        for (int j = 0; j < 4; ++j) acc[i][j] = (f32x4){0.f, 0.f, 0.f, 0.f};

    // fragment read bases (shorts); swizzled granule per (ks,quad)
    int sw = l16 & 7;
    int ga0 = ((0 * 4 + quad) ^ sw) * 8;  // ks=0 granule offset in shorts
    int ga1 = ((1 * 4 + quad) ^ sw) * 8;  // ks=1
    int arowb = (wm * 64 + l16) * 64;
    int browb = (wn * 64 + l16) * 64;

    FILL(0, 0);
    FILL(1, 1);  // 16 GLD16 in flight per wave

#pragma unroll
    for (int kc = 0; kc < 8; ++kc) {
        int cur = kc & 1;
        if (kc < 7)
            asm volatile("s_waitcnt vmcnt(8)\n\ts_barrier" ::: "memory");
        else
            asm volatile("s_waitcnt vmcnt(0)\n\ts_barrier" ::: "memory");
#pragma unroll
        for (int ks = 0; ks < 2; ++ks) {
            int go = ks ? ga1 : ga0;
            bf16x8 af[4], bfr[4];
#pragma unroll
            for (int t = 0; t < 4; ++t)
                af[t] = *(const bf16x8*)&As[cur][arowb + t * 16 * 64 + go];
#pragma unroll
            for (int t = 0; t < 4; ++t)
                bfr[t] = *(const bf16x8*)&Bs[cur][browb + t * 16 * 64 + go];
#pragma unroll
            for (int tm = 0; tm < 4; ++tm)
#pragma unroll
                for (int tn = 0; tn < 4; ++tn)
                    acc[tm][tn] = __builtin_amdgcn_mfma_f32_16x16x32_bf16(
                        af[tm], bfr[tn], acc[tm][tn], 0, 0, 0);
        }
        // all waves done reading cur before overwriting it
        asm volatile("s_waitcnt lgkmcnt(0)\n\ts_barrier" ::: "memory");
        if (kc < 6) FILL(cur, kc + 2);
    }
#undef FILL

    // ---- epilogue: clip, margin on label col, exp, per-row reduce ----
    float rowsum[16];
#pragma unroll
    for (int i = 0; i < 16; ++i) rowsum[i] = 0.0f;

#pragma unroll
    for (int tm = 0; tm < 4; ++tm) {
#pragma unroll
        for (int r = 0; r < 4; ++r) {
            int m_local = wm * 64 + tm * 16 + quad * 4 + r;
            int lbl = sLbl[m_local];
            float rs = 0.0f;
#pragma unroll
            for (int tn = 0; tn < 4; ++tn) {
                float c = acc[tm][tn][r];
                c = fminf(fmaxf(c, CLIP_LO), CLIP_HI);
                int col = n0 + wn * 64 + tn * 16 + l16;
                float t = c;
                if (col == lbl) {
                    float sn = sqrtf(fmaxf(1.0f - c * c, 0.0f));
                    float ph = c * COS_M - sn * SIN_M;
                    ph = (c > TH_C) ? ph : (c - MM_C);
                    t = ph;
                    phiS[mb * 128 + m_local] = S_SCALE * ph;
                }
                float ex = (col < NCLS) ? __expf(S_SCALE * t - 64.0f) : 0.0f;
                rs += ex;
            }
            rowsum[tm * 4 + r] = rs;
        }
    }
#pragma unroll
    for (int idx = 0; idx < 16; ++idx) {
        float v = rowsum[idx];
        v += __shfl_xor(v, 1, 64);
        v += __shfl_xor(v, 2, 64);
        v += __shfl_xor(v, 4, 64);
        v += __shfl_xor(v, 8, 64);
        if (l16 == idx) {
            int tm = idx >> 2, r = idx & 3;
            int m_local = wm * 64 + tm * 16 + quad * 4 + r;
            atomicAdd(&sumexp[mb * 128 + m_local], v);
        }
    }
}

// ---------------- kernel 4: nll + mean ----------------
__global__ void k_final(const float* __restrict__ sumexp,
                        const float* __restrict__ phiS,
                        float* __restrict__ out) {
    int tid = threadIdx.x;  // 512
    float nll = 64.0f + logf(sumexp[tid]) - phiS[tid];
    for (int m = 1; m < 64; m <<= 1) nll += __shfl_xor(nll, m, 64);
    __shared__ float ws[8];
    if ((tid & 63) == 0) ws[tid >> 6] = nll;
    __syncthreads();
    if (tid == 0) {
        float s = 0.0f;
        for (int j = 0; j < 8; ++j) s += ws[j];
        out[0] = s / (float)BATCH;
    }
}

// ---------------- launch ----------------
extern "C" void kernel_launch(void* const* d_in, const int* in_sizes, int n_in,
                              void* d_out, int out_size, void* d_ws,
                              size_t ws_size, hipStream_t stream) {
    const float* emb = (const float*)d_in[0];
    const float* wgt = (const float*)d_in[1];
    const int* lbl = (const int*)d_in[2];

    char* ws = (char*)d_ws;
    short* wbf = (short*)ws;                   // 102,400,000 B
    short* ebf = (short*)(ws + 102400000);     // 524,288 B
    float* sumexp = (float*)(ws + 102924288);  // 2048 B
    float* phiS = (float*)(ws + 102926336);    // 2048 B

    k_norm_e<<<dim3(BATCH), dim3(128), 0, stream>>>(emb, ebf, sumexp);
    k_norm_w<<<dim3(NCLS / 4), dim3(256), 0, stream>>>(wgt, wbf);
    k_gemm<<<dim3(3136), dim3(256), 0, stream>>>(ebf, wbf, lbl, sumexp, phiS);
    k_final<<<dim3(1), dim3(512), 0, stream>>>(sumexp, phiS, (float*)d_out);
}

// Round 5
// 433.843 us; speedup vs baseline: 1.4821x; 1.1242x over previous
//
#include <hip/hip_runtime.h>
#include <math.h>

// ---------------- constants ----------------
#define BATCH 512
#define DIM 512
#define NCLS 100000
#define NB_TILES 782  // ceil(NCLS/128)
#define S_SCALE 64.0f
#define COS_M 0.8775825618903728f
#define SIN_M 0.479425538604203f
#define TH_C (-0.8775825618903728f)
#define MM_C 0.2397127693021015f
#define CLIP_LO (-1.0f + 1e-7f)
#define CLIP_HI (1.0f - 1e-7f)

typedef __attribute__((ext_vector_type(8))) short bf16x8;
typedef __attribute__((ext_vector_type(4))) float f32x4;

__device__ __forceinline__ unsigned int f2bf(float x) {
    union { float f; unsigned int u; } v;
    v.f = x;
    return (v.u + 0x7fffu + ((v.u >> 16) & 1u)) >> 16;
}
__device__ __forceinline__ unsigned int pack2(float lo, float hi) {
    return f2bf(lo) | (f2bf(hi) << 16);
}

// ---------------- kernel 1: normalize embeddings -> bf16, zero sumexp -------
__global__ void k_norm_e(const float* __restrict__ e, short* __restrict__ ebf,
                         float* __restrict__ sumexpz) {
    int row = blockIdx.x;  // 512 rows
    int tid = threadIdx.x; // 128 threads, 4 floats each
    const float4* p = (const float4*)(e + (size_t)row * DIM);
    float4 v = p[tid];
    float ss = v.x * v.x + v.y * v.y + v.z * v.z + v.w * v.w;
    for (int m = 1; m < 64; m <<= 1) ss += __shfl_xor(ss, m, 64);
    __shared__ float wss[2];
    if ((tid & 63) == 0) wss[tid >> 6] = ss;
    __syncthreads();
    float inv = 1.0f / fmaxf(sqrtf(wss[0] + wss[1]), 1e-12f);
    ushort4 o;
    o.x = (unsigned short)f2bf(v.x * inv);
    o.y = (unsigned short)f2bf(v.y * inv);
    o.z = (unsigned short)f2bf(v.z * inv);
    o.w = (unsigned short)f2bf(v.w * inv);
    ((ushort4*)(ebf + (size_t)row * DIM))[tid] = o;
    if (tid == 0) sumexpz[row] = 0.0f;
}

// ---------------- kernel 2: fused GEMM + w-normalize + margin + sumexp ------
// 128x128 tile, BK=32, register-staged (global->VGPR->LDS) software pipeline.
// W read as fp32 ONCE (no wbf pass / no 103MB ws): convert to bf16 while
// staging, accumulate ssq per row, apply rsqrt in epilogue.
// XOR swizzle slot = granule ^ ((r ^ (r>>2))&3): 2-way (free) frag reads,
// conflict-free full-row writes. Raw lgkm-only barriers keep the kc+1 global
// prefetch in flight across the barrier.
// BK=32 keeps prefetch live set to 24 VGPR (R3's 48 at BK=64 spilled);
// unroll 1 prevents cross-iteration hoisting.
__global__ __launch_bounds__(256, 2) void k_gemm(
    const short* __restrict__ ebf, const float* __restrict__ wgt,
    const int* __restrict__ labels, float* __restrict__ sumexp,
    float* __restrict__ phiS) {
    __shared__ __align__(16) short As[128 * 32];
    __shared__ __align__(16) short Bs[128 * 32];
    __shared__ int sLbl[128];
    __shared__ float sWn[128];

    int bx = blockIdx.x;
    int nb = (bx >> 5) * 8 + (bx & 7);  // mb-siblings share bx%8 (same XCD)
    if (nb >= NB_TILES) return;
    int mb = (bx >> 3) & 3;
    int n0 = nb * 128;

    int tid = threadIdx.x;
    int lane = tid & 63;
    int wv = tid >> 6;
    int wm = wv >> 1, wn = wv & 1;
    int quad = lane >> 4, l16 = lane & 15;

    if (tid < 128) sLbl[tid] = labels[mb * 128 + tid];

    // --- A staging: 2 int4/thread, rows 64*i + (tid>>2), granule tid&3 ---
    int ar = tid >> 2;
    const short* gA = ebf + (size_t)(mb * 128 + ar) * DIM + (tid & 3) * 8;
    int akey = ((tid >> 2) ^ (tid >> 4)) & 3;
    int aw0 = ar * 32 + ((tid & 3) ^ akey) * 8;  // LDS short idx, + i*64*32

    // --- B staging: 4 float4/thread, rows 32*i + (tid>>3), floats (tid&7)*4 --
    int br = tid >> 3;
    int gBo[4];
#pragma unroll
    for (int i = 0; i < 4; ++i) {
        int wr = n0 + 32 * i + br;
        if (wr > NCLS - 1) wr = NCLS - 1;
        gBo[i] = wr * DIM + (tid & 7) * 4;
    }
    int bkey = ((tid >> 3) ^ (tid >> 5)) & 3;
    int bw0 = br * 32 + (((tid & 7) >> 1) ^ bkey) * 8 + (tid & 1) * 4;

    f32x4 acc[4][4];
#pragma unroll
    for (int i = 0; i < 4; ++i)
#pragma unroll
        for (int j = 0; j < 4; ++j) acc[i][j] = (f32x4){0.f, 0.f, 0.f, 0.f};
    float ssq[4] = {0.f, 0.f, 0.f, 0.f};

    // --- fragment read bases (key uniform across t: row&15 == l16 pattern) --
    int go = (quad ^ ((l16 ^ (l16 >> 2)) & 3)) * 8;
    int arowb = (wm * 64 + l16) * 32 + go;
    int browb = (wn * 64 + l16) * 32 + go;

    // --- preload kc=0 ---
    int4 ra0 = *(const int4*)(gA);
    int4 ra1 = *(const int4*)(gA + 64 * DIM);
    float4 rb0 = *(const float4*)(wgt + gBo[0]);
    float4 rb1 = *(const float4*)(wgt + gBo[1]);
    float4 rb2 = *(const float4*)(wgt + gBo[2]);
    float4 rb3 = *(const float4*)(wgt + gBo[3]);

#pragma unroll 1
    for (int kc = 0; kc < 16; ++kc) {
        // ---- write staged regs to LDS (cvt W fp32->bf16, track ssq) ----
        *(int4*)&As[aw0] = ra0;
        *(int4*)&As[64 * 32 + aw0] = ra1;
        {
            uint2 p;
            ssq[0] += rb0.x * rb0.x + rb0.y * rb0.y + rb0.z * rb0.z + rb0.w * rb0.w;
            p.x = pack2(rb0.x, rb0.y); p.y = pack2(rb0.z, rb0.w);
            *(uint2*)&Bs[bw0] = p;
            ssq[1] += rb1.x * rb1.x + rb1.y * rb1.y + rb1.z * rb1.z + rb1.w * rb1.w;
            p.x = pack2(rb1.x, rb1.y); p.y = pack2(rb1.z, rb1.w);
            *(uint2*)&Bs[1024 + bw0] = p;
            ssq[2] += rb2.x * rb2.x + rb2.y * rb2.y + rb2.z * rb2.z + rb2.w * rb2.w;
            p.x = pack2(rb2.x, rb2.y); p.y = pack2(rb2.z, rb2.w);
            *(uint2*)&Bs[2048 + bw0] = p;
            ssq[3] += rb3.x * rb3.x + rb3.y * rb3.y + rb3.z * rb3.z + rb3.w * rb3.w;
            p.x = pack2(rb3.x, rb3.y); p.y = pack2(rb3.z, rb3.w);
            *(uint2*)&Bs[3072 + bw0] = p;
        }
        // ---- prefetch kc+1 (left in flight across the barrier) ----
        if (kc < 15) {
            int ko = (kc + 1) * 32;
            ra0 = *(const int4*)(gA + ko);
            ra1 = *(const int4*)(gA + 64 * DIM + ko);
            rb0 = *(const float4*)(wgt + gBo[0] + ko);
            rb1 = *(const float4*)(wgt + gBo[1] + ko);
            rb2 = *(const float4*)(wgt + gBo[2] + ko);
            rb3 = *(const float4*)(wgt + gBo[3] + ko);
        }
        // wait own LDS writes only; prefetch vmcnt stays outstanding
        asm volatile("s_waitcnt lgkmcnt(0)\n\ts_barrier" ::: "memory");
        // ---- compute: 16 MFMA ----
        {
            bf16x8 af[4], bfr[4];
#pragma unroll
            for (int t = 0; t < 4; ++t)
                af[t] = *(const bf16x8*)&As[arowb + t * 16 * 32];
#pragma unroll
            for (int t = 0; t < 4; ++t)
                bfr[t] = *(const bf16x8*)&Bs[browb + t * 16 * 32];
#pragma unroll
            for (int tm = 0; tm < 4; ++tm)
#pragma unroll
                for (int tn = 0; tn < 4; ++tn)
                    acc[tm][tn] = __builtin_amdgcn_mfma_f32_16x16x32_bf16(
                        af[tm], bfr[tn], acc[tm][tn], 0, 0, 0);
        }
        // frag reads are lgkm-drained before their MFMA uses; plain barrier
        asm volatile("s_barrier" ::: "memory");
    }

    // ---- finalize W norms: reduce ssq over the 8 threads sharing each row --
#pragma unroll
    for (int i = 0; i < 4; ++i) {
        float s = ssq[i];
        s += __shfl_xor(s, 1, 64);
        s += __shfl_xor(s, 2, 64);
        s += __shfl_xor(s, 4, 64);
        if ((lane & 7) == 0)
            sWn[32 * i + br] = 1.0f / fmaxf(sqrtf(s), 1e-12f);
    }
    asm volatile("s_waitcnt lgkmcnt(0)\n\ts_barrier" ::: "memory");

    float wscale[4];
#pragma unroll
    for (int tn = 0; tn < 4; ++tn) wscale[tn] = sWn[wn * 64 + tn * 16 + l16];

    // ---- epilogue: scale, clip, margin on label col, exp, per-row reduce --
    float rowsum[16];
#pragma unroll
    for (int i = 0; i < 16; ++i) rowsum[i] = 0.0f;

#pragma unroll
    for (int tm = 0; tm < 4; ++tm) {
#pragma unroll
        for (int r = 0; r < 4; ++r) {
            int m_local = wm * 64 + tm * 16 + quad * 4 + r;
            int lbl = sLbl[m_local];
            float rs = 0.0f;
#pragma unroll
            for (int tn = 0; tn < 4; ++tn) {
                float c = acc[tm][tn][r] * wscale[tn];
                c = fminf(fmaxf(c, CLIP_LO), CLIP_HI);
                int col = n0 + wn * 64 + tn * 16 + l16;
                float t = c;
                if (col == lbl) {
                    float sn = sqrtf(fmaxf(1.0f - c * c, 0.0f));
                    float ph = c * COS_M - sn * SIN_M;
                    ph = (c > TH_C) ? ph : (c - MM_C);
                    t = ph;
                    phiS[mb * 128 + m_local] = S_SCALE * ph;
                }
                float ex = (col < NCLS) ? __expf(S_SCALE * t - 64.0f) : 0.0f;
                rs += ex;
            }
            rowsum[tm * 4 + r] = rs;
        }
    }
#pragma unroll
    for (int idx = 0; idx < 16; ++idx) {
        float v = rowsum[idx];
        v += __shfl_xor(v, 1, 64);
        v += __shfl_xor(v, 2, 64);
        v += __shfl_xor(v, 4, 64);
        v += __shfl_xor(v, 8, 64);
        if (l16 == idx) {
            int tm = idx >> 2, r = idx & 3;
            int m_local = wm * 64 + tm * 16 + quad * 4 + r;
            atomicAdd(&sumexp[mb * 128 + m_local], v);
        }
    }
}

// ---------------- kernel 3: nll + mean ----------------
__global__ void k_final(const float* __restrict__ sumexp,
                        const float* __restrict__ phiS,
                        float* __restrict__ out) {
    int tid = threadIdx.x;  // 512
    float nll = 64.0f + logf(sumexp[tid]) - phiS[tid];
    for (int m = 1; m < 64; m <<= 1) nll += __shfl_xor(nll, m, 64);
    __shared__ float ws[8];
    if ((tid & 63) == 0) ws[tid >> 6] = nll;
    __syncthreads();
    if (tid == 0) {
        float s = 0.0f;
        for (int j = 0; j < 8; ++j) s += ws[j];
        out[0] = s / (float)BATCH;
    }
}

// ---------------- launch ----------------
extern "C" void kernel_launch(void* const* d_in, const int* in_sizes, int n_in,
                              void* d_out, int out_size, void* d_ws,
                              size_t ws_size, hipStream_t stream) {
    const float* emb = (const float*)d_in[0];
    const float* wgt = (const float*)d_in[1];
    const int* lbl = (const int*)d_in[2];

    char* ws = (char*)d_ws;
    short* ebf = (short*)ws;                // 524,288 B
    float* sumexp = (float*)(ws + 524288);  // 2048 B
    float* phiS = (float*)(ws + 526336);    // 2048 B

    k_norm_e<<<dim3(BATCH), dim3(128), 0, stream>>>(emb, ebf, sumexp);
    k_gemm<<<dim3(3136), dim3(256), 0, stream>>>(ebf, wgt, lbl, sumexp, phiS);
    k_final<<<dim3(1), dim3(512), 0, stream>>>(sumexp, phiS, (float*)d_out);
}